// Round 5
// baseline (3538.569 us; speedup 1.0000x reference)
//
#include <hip/hip_runtime.h>
#include <math.h>

#define NM 16
#define TT 8192
#define HH 128
#define G3 384
#define BT 512

#define NLOG2E (-1.4426950408889634f)
#define P2LOG2E (2.8853900817779268f)

typedef _Float16 half_t;
typedef _Float16 h2_t __attribute__((ext_vector_type(2)));

#if defined(__has_builtin)
#if __has_builtin(__builtin_amdgcn_fdot2)
#define HAS_FDOT2 1
#endif
#if __has_builtin(__builtin_amdgcn_exp2f)
#define HAS_EXP2 1
#endif
#endif

__device__ __forceinline__ float dot2acc(h2_t a, h2_t b, float c) {
#ifdef HAS_FDOT2
    return __builtin_amdgcn_fdot2(a, b, c, false);
#else
    return fmaf((float)a[0], (float)b[0], fmaf((float)a[1], (float)b[1], c));
#endif
}

__device__ __forceinline__ h2_t u2h(unsigned int u) {
    return __builtin_bit_cast(h2_t, u);
}

__device__ __forceinline__ float fast_exp2(float x) {
#ifdef HAS_EXP2
    return __builtin_amdgcn_exp2f(x);           // raw v_exp_f32
#else
    return __exp2f(x);
#endif
}

__device__ __forceinline__ float fast_rcp(float x) {
    return __builtin_amdgcn_rcpf(x);
}

// sum over the 4 lanes of a quad (two DPP quad_perm stages, pure VALU)
__device__ __forceinline__ float quad_sum(float x) {
    int a = __builtin_amdgcn_mov_dpp(__builtin_bit_cast(int, x), 0xB1, 0xF, 0xF, true); // [1,0,3,2]
    x += __builtin_bit_cast(float, a);
    int b = __builtin_amdgcn_mov_dpp(__builtin_bit_cast(int, x), 0x4E, 0xF, 0xF, true); // [2,3,0,1]
    x += __builtin_bit_cast(float, b);
    return x;
}

// ---------------- K0: per-mic standardize (mean, std ddof=1) ----------------
__global__ void k_norm(const float* __restrict__ samples, float* __restrict__ s_out) {
    int mic = blockIdx.x;
    const float* x = samples + (long)mic * TT;
    __shared__ float red[256];
    int tid = threadIdx.x;
    float acc = 0.f;
    for (int i = tid; i < TT; i += 256) acc += x[i];
    red[tid] = acc; __syncthreads();
    for (int off = 128; off > 0; off >>= 1) { if (tid < off) red[tid] += red[tid + off]; __syncthreads(); }
    float mu = red[0] / (float)TT;
    __syncthreads();
    float acc2 = 0.f;
    for (int i = tid; i < TT; i += 256) { float d = x[i] - mu; acc2 += d * d; }
    red[tid] = acc2; __syncthreads();
    for (int off = 128; off > 0; off >>= 1) { if (tid < off) red[tid] += red[tid + off]; __syncthreads(); }
    float inv = rsqrtf(red[0] / (float)(TT - 1));
    for (int i = tid; i < TT; i += 256) s_out[(long)mic * TT + i] = (x[i] - mu) * inv;
}

// ---------------- K1: gi rows, with b_hh fold (r/z) and log2e pre-scaling ----------------
// rows 0..255 (r,z gates): gi = -log2e * (w_ih@s + b_ih + b_hh)
// rows 256..383 (n gate):  gi = 2*log2e * (w_ih@s + b_ih)
__global__ void k_gi(const float* __restrict__ s, const float* __restrict__ w_ih,
                     const float* __restrict__ b_ih, const float* __restrict__ b_hh,
                     float* __restrict__ gi) {
    int t = blockIdx.x;
    __shared__ float sv[NM];
    int tid = threadIdx.x;            // 0..383
    if (tid < NM) sv[tid] = s[(long)tid * TT + t];
    __syncthreads();
    float acc = b_ih[tid];
    if (tid < 2 * HH) acc += b_hh[tid];
    const float* wr = w_ih + tid * NM;
#pragma unroll
    for (int m = 0; m < NM; ++m) acc += wr[m] * sv[m];
    float scale = (tid < 2 * HH) ? NLOG2E : P2LOG2E;
    gi[(long)t * G3 + tid] = acc * scale;
}

// ---------------- K2: sequential GRU scan ----------------
// 512 threads = 8 waves (2/SIMD for latency interleave). Thread t: h-index
// j=t>>2, k-quarter q=t&3 (32 cols). 48 dot2/thread (f16, log2e-folded).
// Quad-reduce via 2x DPP quad_perm; pointwise in-lane (exp2+rcp, no divides,
// no muls on the chain); ONE barrier/step (double-buffered f16 h in LDS).
__launch_bounds__(BT, 1)
__global__ void k_gru(const float* __restrict__ gi, const float* __restrict__ w_hh,
                      const float* __restrict__ b_hh, float* __restrict__ h_out) {
    __shared__ __align__(16) half_t hb[2][HH];
    int tid = threadIdx.x;            // 0..511
    int j = tid >> 2;                 // 0..127
    int q = tid & 3;                  // k-quarter
    int k0 = q * 32;                  // element offset into h

    // three gate quarter-rows as packed f16, pre-scaled for exp2 math
    h2_t wr[16], wz[16], wn[16];
    {
        const float2* r2 = (const float2*)(w_hh + (long)j * HH + k0);
        const float2* z2 = (const float2*)(w_hh + (long)(HH + j) * HH + k0);
        const float2* n2 = (const float2*)(w_hh + (long)(2 * HH + j) * HH + k0);
#pragma unroll
        for (int k = 0; k < 16; ++k) {
            float2 a = r2[k]; wr[k] = h2_t{(half_t)(a.x * NLOG2E), (half_t)(a.y * NLOG2E)};
            float2 b = z2[k]; wz[k] = h2_t{(half_t)(b.x * NLOG2E), (half_t)(b.y * NLOG2E)};
            float2 c = n2[k]; wn[k] = h2_t{(half_t)(c.x * P2LOG2E), (half_t)(c.y * P2LOG2E)};
        }
    }
    float bhn = b_hh[2 * HH + j] * P2LOG2E;

    if (tid < HH) hb[0][tid] = (half_t)0.f;
    float h_reg = 0.f;
    const float* gp = gi;             // row t=0 (uniform pointer, += G3 per step)
    float gA = gp[j], gB = gp[HH + j], gC = gp[2 * HH + j];
    __syncthreads();

    int p = 0;
    for (int t = 0; t < TT; ++t) {
        // prefetch next gi row (row TT is a dead pad; loads hidden under dots)
        gp += G3;
        float nA = gp[j], nB = gp[HH + j], nC = gp[2 * HH + j];

        // h quarter-slice: 4x ds_read_b128 (16-lane broadcast, conflict-free)
        const uint4* hp = (const uint4*)(&hb[p][k0]);
        float ar0 = 0.f, ar1 = 0.f, az0 = 0.f, az1 = 0.f, an0 = 0.f, an1 = 0.f;
#pragma unroll
        for (int c = 0; c < 4; ++c) {
            uint4 hv = hp[c];
            h2_t p0 = u2h(hv.x), p1 = u2h(hv.y), p2 = u2h(hv.z), p3 = u2h(hv.w);
            int k = c * 4;
            ar0 = dot2acc(wr[k], p0, ar0); ar1 = dot2acc(wr[k + 1], p1, ar1);
            ar0 = dot2acc(wr[k + 2], p2, ar0); ar1 = dot2acc(wr[k + 3], p3, ar1);
            az0 = dot2acc(wz[k], p0, az0); az1 = dot2acc(wz[k + 1], p1, az1);
            az0 = dot2acc(wz[k + 2], p2, az0); az1 = dot2acc(wz[k + 3], p3, az1);
            an0 = dot2acc(wn[k], p0, an0); an1 = dot2acc(wn[k + 1], p1, an1);
            an0 = dot2acc(wn[k + 2], p2, an0); an1 = dot2acc(wn[k + 3], p3, an1);
        }
        // reduce across the 4 k-quarters (same quad) via DPP
        float ar = quad_sum(ar0 + ar1);   // = -log2e * (Wr@h)
        float az = quad_sum(az0 + az1);
        float an = quad_sum(an0 + an1);   // = 2log2e * (Wn@h)

        // pointwise (duplicated across quad lanes, all in-lane):
        // sigmoid(x) = rcp(1 + 2^(-x*log2e)); tanh(x) = 1 - 2*rcp(1 + 2^(2x*log2e))
        float r = fast_rcp(1.f + fast_exp2(gA + ar));
        float z = fast_rcp(1.f + fast_exp2(gB + az));
        float yn = fmaf(r, an + bhn, gC);
        float e2 = fast_exp2(yn);
        float n = fmaf(-2.f, fast_rcp(e2 + 1.f), 1.f);
        h_reg = fmaf(z, h_reg - n, n);
        if (q == 0) hb[1 - p][j] = (half_t)h_reg;

        gA = nA; gB = nB; gC = nC;
        __syncthreads();
        p ^= 1;
    }
    if (q == 0) h_out[j] = h_reg;
}

// ---------------- K3: v = w_post@h + b_post; c from rank-1 eigh model ----------------
__global__ void k_eig(const float* __restrict__ h_last, const float* __restrict__ w_post,
                      const float* __restrict__ b_post, const int* __restrict__ ns_p,
                      float* __restrict__ c_out) {
    __shared__ float v[NM];
    int tid = threadIdx.x;
    if (tid < NM) {
        float acc = b_post[tid];
        const float* wr = w_post + tid * HH;
        for (int k = 0; k < HH; ++k) acc += wr[k] * h_last[k];
        v[tid] = acc;
    }
    __syncthreads();
    if (tid == 0) {
        float S1 = 0.f, vv = 0.f;
        for (int i = 0; i < NM; ++i) { S1 += v[i]; vv += v[i] * v[i]; }
        // ||p||^2 = ||P_null 1||^2 ; null dim = NM-1 (rank-1 cov)
        float pp = (float)NM - S1 * S1 / vv;
        int nn = NM - ns_p[0];                      // 13 noise dirs kept of 15
        // chaos-expectation model of LAPACK's degenerate-basis choice:
        float kept = pp * ((float)nn / (float)(NM - 1));
        c_out[0] = 1.f / sqrtf(kept);               // spectrum value (constant over thetas)
    }
}

// ---------------- K4: h1 = gelu(c * rowsum(w1) + b1) ----------------
__global__ void k_h1(const float* __restrict__ w1, const float* __restrict__ b1,
                     const float* __restrict__ c_p, float* __restrict__ h1) {
    int row = blockIdx.x;            // 0..255
    int tid = threadIdx.x;           // 0..255
    const float4* wr = (const float4*)(w1 + (long)row * 65536);
    float acc = 0.f;
    for (int i = tid; i < 16384; i += 256) { float4 x = wr[i]; acc += (x.x + x.y) + (x.z + x.w); }
    __shared__ float red[256];
    red[tid] = acc; __syncthreads();
    for (int off = 128; off > 0; off >>= 1) { if (tid < off) red[tid] += red[tid + off]; __syncthreads(); }
    if (tid == 0) {
        float x = c_p[0] * red[0] + b1[row];
        h1[row] = 0.5f * x * (1.f + erff(x * 0.70710678118654752f));
    }
}

// ---------------- K5: h2 = gelu(w2@h1+b2); out = sigmoid(w3@h2+b3)*2pi ----------------
__global__ void k_out(const float* __restrict__ h1, const float* __restrict__ w2,
                      const float* __restrict__ b2, const float* __restrict__ w3,
                      const float* __restrict__ b3, float* __restrict__ out) {
    __shared__ float h2[256];
    int tid = threadIdx.x;           // 0..255
    float acc = b2[tid];
    const float* wr = w2 + tid * 256;
    for (int k = 0; k < 256; ++k) acc += wr[k] * h1[k];
    h2[tid] = 0.5f * acc * (1.f + erff(acc * 0.70710678118654752f));
    __syncthreads();
    if (tid < NM) {
        float a = b3[tid];
        const float* wr3 = w3 + tid * 256;
        for (int k = 0; k < 256; ++k) a += wr3[k] * h2[k];
        out[tid] = (1.f / (1.f + expf(-a))) * 6.283185307179586f;
    }
}

extern "C" void kernel_launch(void* const* d_in, const int* in_sizes, int n_in,
                              void* d_out, int out_size, void* d_ws, size_t ws_size,
                              hipStream_t stream) {
    const float* samples = (const float*)d_in[0];
    const int*   n_src   = (const int*)d_in[1];
    // d_in[2] = mic_locations: dead (mf==0 -> atheta==1)
    const float* w_ih   = (const float*)d_in[3];
    const float* w_hh   = (const float*)d_in[4];
    const float* b_ih   = (const float*)d_in[5];
    const float* b_hh   = (const float*)d_in[6];
    const float* w_post = (const float*)d_in[7];
    const float* b_post = (const float*)d_in[8];
    const float* w1     = (const float*)d_in[9];
    const float* b1     = (const float*)d_in[10];
    const float* w2     = (const float*)d_in[11];
    const float* b2     = (const float*)d_in[12];
    const float* w3     = (const float*)d_in[13];
    const float* b3     = (const float*)d_in[14];
    float* out = (float*)d_out;

    float* ws     = (float*)d_ws;
    float* s      = ws;                        // 16*8192
    float* gi     = s + NM * TT;               // (8192+1)*384  (row TT = dead prefetch pad)
    float* h_last = gi + (long)(TT + 1) * G3;  // 128
    float* c_p    = h_last + HH;               // 1
    float* h1     = c_p + 1;                   // 256

    hipLaunchKernelGGL(k_norm, dim3(NM),   dim3(256), 0, stream, samples, s);
    hipLaunchKernelGGL(k_gi,   dim3(TT),   dim3(G3),  0, stream, s, w_ih, b_ih, b_hh, gi);
    hipLaunchKernelGGL(k_gru,  dim3(1),    dim3(BT),  0, stream, gi, w_hh, b_hh, h_last);
    hipLaunchKernelGGL(k_eig,  dim3(1),    dim3(64),  0, stream, h_last, w_post, b_post, n_src, c_p);
    hipLaunchKernelGGL(k_h1,   dim3(256),  dim3(256), 0, stream, w1, b1, c_p, h1);
    hipLaunchKernelGGL(k_out,  dim3(1),    dim3(256), 0, stream, h1, w2, b2, w3, b3, out);
}

// Round 6
// 3411.644 us; speedup vs baseline: 1.0372x; 1.0372x over previous
//
#include <hip/hip_runtime.h>
#include <math.h>

#define NM 16
#define TT 8192
#define HH 128
#define G3 384
#define BT 256

#define NLOG2E (-1.4426950408889634f)
#define P2LOG2E (2.8853900817779268f)

typedef _Float16 half_t;
typedef _Float16 h2_t __attribute__((ext_vector_type(2)));

#if defined(__has_builtin)
#if __has_builtin(__builtin_amdgcn_fdot2)
#define HAS_FDOT2 1
#endif
#if __has_builtin(__builtin_amdgcn_exp2f)
#define HAS_EXP2 1
#endif
#endif

__device__ __forceinline__ float dot2acc(h2_t a, h2_t b, float c) {
#ifdef HAS_FDOT2
    return __builtin_amdgcn_fdot2(a, b, c, false);
#else
    return fmaf((float)a[0], (float)b[0], fmaf((float)a[1], (float)b[1], c));
#endif
}

__device__ __forceinline__ h2_t u2h(unsigned int u) {
    return __builtin_bit_cast(h2_t, u);
}

__device__ __forceinline__ float fast_exp2(float x) {
#ifdef HAS_EXP2
    return __builtin_amdgcn_exp2f(x);           // raw v_exp_f32
#else
    return __exp2f(x);
#endif
}

__device__ __forceinline__ float fast_rcp(float x) {
    return __builtin_amdgcn_rcpf(x);
}

// pair-sum across lanes (2j, 2j+1) via DPP quad_perm [1,0,3,2] — pure VALU
__device__ __forceinline__ float pair_sum(float x) {
    int y = __builtin_amdgcn_mov_dpp(__builtin_bit_cast(int, x), 0xB1, 0xF, 0xF, true);
    return x + __builtin_bit_cast(float, y);
}

// ---------------- K0: per-mic standardize (mean, std ddof=1) ----------------
__global__ void k_norm(const float* __restrict__ samples, float* __restrict__ s_out) {
    int mic = blockIdx.x;
    const float* x = samples + (long)mic * TT;
    __shared__ float red[256];
    int tid = threadIdx.x;
    float acc = 0.f;
    for (int i = tid; i < TT; i += 256) acc += x[i];
    red[tid] = acc; __syncthreads();
    for (int off = 128; off > 0; off >>= 1) { if (tid < off) red[tid] += red[tid + off]; __syncthreads(); }
    float mu = red[0] / (float)TT;
    __syncthreads();
    float acc2 = 0.f;
    for (int i = tid; i < TT; i += 256) { float d = x[i] - mu; acc2 += d * d; }
    red[tid] = acc2; __syncthreads();
    for (int off = 128; off > 0; off >>= 1) { if (tid < off) red[tid] += red[tid + off]; __syncthreads(); }
    float inv = rsqrtf(red[0] / (float)(TT - 1));
    for (int i = tid; i < TT; i += 256) s_out[(long)mic * TT + i] = (x[i] - mu) * inv;
}

// ---------------- K1: gi rows, with b_hh fold (r/z) and log2e pre-scaling ----------------
// rows 0..255 (r,z gates): gi = -log2e * (w_ih@s + b_ih + b_hh)
// rows 256..383 (n gate):  gi = 2*log2e * (w_ih@s + b_ih)
__global__ void k_gi(const float* __restrict__ s, const float* __restrict__ w_ih,
                     const float* __restrict__ b_ih, const float* __restrict__ b_hh,
                     float* __restrict__ gi) {
    int t = blockIdx.x;
    __shared__ float sv[NM];
    int tid = threadIdx.x;            // 0..383
    if (tid < NM) sv[tid] = s[(long)tid * TT + t];
    __syncthreads();
    float acc = b_ih[tid];
    if (tid < 2 * HH) acc += b_hh[tid];
    const float* wr = w_ih + tid * NM;
#pragma unroll
    for (int m = 0; m < NM; ++m) acc += wr[m] * sv[m];
    float scale = (tid < 2 * HH) ? NLOG2E : P2LOG2E;
    gi[(long)t * G3 + tid] = acc * scale;
}

// ---------------- K2: sequential GRU scan ----------------
// 256 threads = 4 waves (1/SIMD — R5 showed 2/SIMD regresses: barrier-locked
// waves don't overlap, they just double pointwise issue). Thread t: h-index
// j=t>>1, k-half=t&1 (64 cols). Dots via packed v_pk_fma_f16 (full-rate
// VOP3P) into 4 independent h2 accumulators per gate (8 products per f16
// slot), combined by 4 dot2-with-ones. DPP pair-reduce; exp2+rcp pointwise
// (log2e pre-folded); ONE barrier/step (double-buffered f16 h in LDS).
__launch_bounds__(BT, 1)
__global__ void k_gru(const float* __restrict__ gi, const float* __restrict__ w_hh,
                      const float* __restrict__ b_hh, float* __restrict__ h_out) {
    __shared__ __align__(16) half_t hb[2][HH];
    int tid = threadIdx.x;            // 0..255
    int j = tid >> 1;                 // 0..127
    int half = tid & 1;               // k-half
    int k0 = half * 64;

    // three gate half-rows as packed f16, pre-scaled for exp2 math
    h2_t wr[32], wz[32], wn[32];
    {
        const float2* r2 = (const float2*)(w_hh + (long)j * HH + k0);
        const float2* z2 = (const float2*)(w_hh + (long)(HH + j) * HH + k0);
        const float2* n2 = (const float2*)(w_hh + (long)(2 * HH + j) * HH + k0);
#pragma unroll
        for (int k = 0; k < 32; ++k) {
            float2 a = r2[k]; wr[k] = h2_t{(half_t)(a.x * NLOG2E), (half_t)(a.y * NLOG2E)};
            float2 b = z2[k]; wz[k] = h2_t{(half_t)(b.x * NLOG2E), (half_t)(b.y * NLOG2E)};
            float2 c = n2[k]; wn[k] = h2_t{(half_t)(c.x * P2LOG2E), (half_t)(c.y * P2LOG2E)};
        }
    }
    float bhn = b_hh[2 * HH + j] * P2LOG2E;
    const h2_t one2 = h2_t{(half_t)1.f, (half_t)1.f};

    if (tid < HH) hb[0][tid] = (half_t)0.f;
    float h_reg = 0.f;
    const float* gp = gi;             // uniform pointer, += G3 per step
    float gA = gp[j], gB = gp[HH + j], gC = gp[2 * HH + j];
    __syncthreads();

    int p = 0;
    for (int t = 0; t < TT; ++t) {
        // prefetch next gi row (row TT is a dead pad; loads hidden under dots)
        gp += G3;
        float nA = gp[j], nB = gp[HH + j], nC = gp[2 * HH + j];

        // h half-slice: 8x ds_read_b128, dwords bit-cast to h2 (no pack VALU)
        const uint4* hp = (const uint4*)(&hb[p][k0]);
        // 4 independent packed-f16 accumulators per gate (8 products/f16 slot)
        h2_t cr0 = {}, cr1 = {}, cr2 = {}, cr3 = {};
        h2_t cz0 = {}, cz1 = {}, cz2 = {}, cz3 = {};
        h2_t cn0 = {}, cn1 = {}, cn2 = {}, cn3 = {};
#pragma unroll
        for (int c = 0; c < 8; ++c) {
            uint4 hv = hp[c];
            h2_t p0 = u2h(hv.x), p1 = u2h(hv.y), p2 = u2h(hv.z), p3 = u2h(hv.w);
            int k = c * 4;
            cr0 = wr[k] * p0 + cr0; cr1 = wr[k + 1] * p1 + cr1;
            cr2 = wr[k + 2] * p2 + cr2; cr3 = wr[k + 3] * p3 + cr3;
            cz0 = wz[k] * p0 + cz0; cz1 = wz[k + 1] * p1 + cz1;
            cz2 = wz[k + 2] * p2 + cz2; cz3 = wz[k + 3] * p3 + cz3;
            cn0 = wn[k] * p0 + cn0; cn1 = wn[k + 1] * p1 + cn1;
            cn2 = wn[k + 2] * p2 + cn2; cn3 = wn[k + 3] * p3 + cn3;
        }
        // fold packed accumulators to f32 (dot2 with ones, two short chains)
        float ar = dot2acc(cr1, one2, dot2acc(cr0, one2, 0.f))
                 + dot2acc(cr3, one2, dot2acc(cr2, one2, 0.f));
        float az = dot2acc(cz1, one2, dot2acc(cz0, one2, 0.f))
                 + dot2acc(cz3, one2, dot2acc(cz2, one2, 0.f));
        float an = dot2acc(cn1, one2, dot2acc(cn0, one2, 0.f))
                 + dot2acc(cn3, one2, dot2acc(cn2, one2, 0.f));
        // pair-reduce across k-halves (lane^1) via DPP
        ar = pair_sum(ar);                // = -log2e * (Wr@h + b)
        az = pair_sum(az);
        an = pair_sum(an);                // = 2log2e * (Wn@h)

        // pointwise (both pair lanes compute identically, all in-lane):
        // sigmoid(x) = rcp(1 + 2^(-x*log2e)); tanh(x) = 1 - 2*rcp(1 + 2^(2x*log2e))
        float r = fast_rcp(1.f + fast_exp2(gA + ar));
        float z = fast_rcp(1.f + fast_exp2(gB + az));
        float yn = fmaf(r, an + bhn, gC);
        float e2 = fast_exp2(yn);
        float n = fmaf(-2.f, fast_rcp(e2 + 1.f), 1.f);
        h_reg = fmaf(z, h_reg - n, n);
        if (!half) hb[1 - p][j] = (half_t)h_reg;

        gA = nA; gB = nB; gC = nC;
        __syncthreads();
        p ^= 1;
    }
    if (!half) h_out[j] = h_reg;
}

// ---------------- K3: v = w_post@h + b_post; c from rank-1 eigh model ----------------
__global__ void k_eig(const float* __restrict__ h_last, const float* __restrict__ w_post,
                      const float* __restrict__ b_post, const int* __restrict__ ns_p,
                      float* __restrict__ c_out) {
    __shared__ float v[NM];
    int tid = threadIdx.x;
    if (tid < NM) {
        float acc = b_post[tid];
        const float* wr = w_post + tid * HH;
        for (int k = 0; k < HH; ++k) acc += wr[k] * h_last[k];
        v[tid] = acc;
    }
    __syncthreads();
    if (tid == 0) {
        float S1 = 0.f, vv = 0.f;
        for (int i = 0; i < NM; ++i) { S1 += v[i]; vv += v[i] * v[i]; }
        // ||p||^2 = ||P_null 1||^2 ; null dim = NM-1 (rank-1 cov)
        float pp = (float)NM - S1 * S1 / vv;
        int nn = NM - ns_p[0];                      // 13 noise dirs kept of 15
        // chaos-expectation model of LAPACK's degenerate-basis choice:
        float kept = pp * ((float)nn / (float)(NM - 1));
        c_out[0] = 1.f / sqrtf(kept);               // spectrum value (constant over thetas)
    }
}

// ---------------- K4: h1 = gelu(c * rowsum(w1) + b1) ----------------
__global__ void k_h1(const float* __restrict__ w1, const float* __restrict__ b1,
                     const float* __restrict__ c_p, float* __restrict__ h1) {
    int row = blockIdx.x;            // 0..255
    int tid = threadIdx.x;           // 0..255
    const float4* wr = (const float4*)(w1 + (long)row * 65536);
    float acc = 0.f;
    for (int i = tid; i < 16384; i += 256) { float4 x = wr[i]; acc += (x.x + x.y) + (x.z + x.w); }
    __shared__ float red[256];
    red[tid] = acc; __syncthreads();
    for (int off = 128; off > 0; off >>= 1) { if (tid < off) red[tid] += red[tid + off]; __syncthreads(); }
    if (tid == 0) {
        float x = c_p[0] * red[0] + b1[row];
        h1[row] = 0.5f * x * (1.f + erff(x * 0.70710678118654752f));
    }
}

// ---------------- K5: h2 = gelu(w2@h1+b2); out = sigmoid(w3@h2+b3)*2pi ----------------
__global__ void k_out(const float* __restrict__ h1, const float* __restrict__ w2,
                      const float* __restrict__ b2, const float* __restrict__ w3,
                      const float* __restrict__ b3, float* __restrict__ out) {
    __shared__ float h2[256];
    int tid = threadIdx.x;           // 0..255
    float acc = b2[tid];
    const float* wr = w2 + tid * 256;
    for (int k = 0; k < 256; ++k) acc += wr[k] * h1[k];
    h2[tid] = 0.5f * acc * (1.f + erff(acc * 0.70710678118654752f));
    __syncthreads();
    if (tid < NM) {
        float a = b3[tid];
        const float* wr3 = w3 + tid * 256;
        for (int k = 0; k < 256; ++k) a += wr3[k] * h2[k];
        out[tid] = (1.f / (1.f + expf(-a))) * 6.283185307179586f;
    }
}

extern "C" void kernel_launch(void* const* d_in, const int* in_sizes, int n_in,
                              void* d_out, int out_size, void* d_ws, size_t ws_size,
                              hipStream_t stream) {
    const float* samples = (const float*)d_in[0];
    const int*   n_src   = (const int*)d_in[1];
    // d_in[2] = mic_locations: dead (mf==0 -> atheta==1)
    const float* w_ih   = (const float*)d_in[3];
    const float* w_hh   = (const float*)d_in[4];
    const float* b_ih   = (const float*)d_in[5];
    const float* b_hh   = (const float*)d_in[6];
    const float* w_post = (const float*)d_in[7];
    const float* b_post = (const float*)d_in[8];
    const float* w1     = (const float*)d_in[9];
    const float* b1     = (const float*)d_in[10];
    const float* w2     = (const float*)d_in[11];
    const float* b2     = (const float*)d_in[12];
    const float* w3     = (const float*)d_in[13];
    const float* b3     = (const float*)d_in[14];
    float* out = (float*)d_out;

    float* ws     = (float*)d_ws;
    float* s      = ws;                        // 16*8192
    float* gi     = s + NM * TT;               // (8192+1)*384  (row TT = dead prefetch pad)
    float* h_last = gi + (long)(TT + 1) * G3;  // 128
    float* c_p    = h_last + HH;               // 1
    float* h1     = c_p + 1;                   // 256

    hipLaunchKernelGGL(k_norm, dim3(NM),   dim3(256), 0, stream, samples, s);
    hipLaunchKernelGGL(k_gi,   dim3(TT),   dim3(G3),  0, stream, s, w_ih, b_ih, b_hh, gi);
    hipLaunchKernelGGL(k_gru,  dim3(1),    dim3(BT),  0, stream, gi, w_hh, b_hh, h_last);
    hipLaunchKernelGGL(k_eig,  dim3(1),    dim3(64),  0, stream, h_last, w_post, b_post, n_src, c_p);
    hipLaunchKernelGGL(k_h1,   dim3(256),  dim3(256), 0, stream, w1, b1, c_p, h1);
    hipLaunchKernelGGL(k_out,  dim3(1),    dim3(256), 0, stream, h1, w2, b2, w3, b3, out);
}